// Round 6
// baseline (1040.046 us; speedup 1.0000x reference)
//
#include <hip/hip_runtime.h>
#include <hip/hip_bf16.h>
#include <hip/hip_cooperative_groups.h>

namespace cg = cooperative_groups;

#define NN 50000
#define NE 800000
#define NCH 196                      // ceil(NN/256) scan chunks
#define CVU 360                      // convert units (92160 elems / 256)
#define ZU  196                      // deg-zero units
#define EBU 3125                     // edge units
#define GBU 782                      // gemm tile units (64 nodes each)
#define RBU 196                      // row units
#define AGU 12500                    // agg units (4 nodes each)

typedef __attribute__((ext_vector_type(8))) __bf16 bf16x8;
typedef __attribute__((ext_vector_type(4))) float float4v;

__device__ __forceinline__ unsigned pack_bf2(float lo, float hi) {
    union { __bf16 b; unsigned short u; } a, c;
    a.b = (__bf16)lo; c.b = (__bf16)hi;
    return (unsigned)a.u | ((unsigned)c.u << 16);
}
__device__ __forceinline__ float2 unpack_bf2(unsigned v) {
    union { unsigned short u; __bf16 b; } lo, hi;
    lo.u = (unsigned short)(v & 0xffff); hi.u = (unsigned short)(v >> 16);
    return make_float2((float)lo.b, (float)hi.b);
}

struct MegaArgs {
    const float* x; const int* ei;
    const float* Ws[3]; const float* Wd[3]; const float* Wl[3];
    const float* as[3]; const float* ad[3]; const float* bb[3]; const float* bl[3];
    __bf16* Wt1; __bf16* Wt2; __bf16* Wt3;
    unsigned* hsb; float* lin; float* als; float* ald; __bf16* hb;
    int* row; int* deg; int* rank; int* exl; int* bsum; int* boff; int* csr_src;
    float* out;
};

// ---- Wt image: [NC][320][72] bf16 per layer (row stride 144 B, pad cols 64..71 = 0) ----
__device__ __forceinline__ void convert_w_part(const float* __restrict__ Ws,
                                               const float* __restrict__ Wd,
                                               const float* __restrict__ Wl,
                                               __bf16* __restrict__ Wt, int i)
{
    int chunk = i / 23040, rem = i % 23040;
    int r = rem / 72, c = rem % 72;
    float v = 0.f;
    if (c < 64) {
        int k = chunk * 64 + c;
        if (r < 128)      v = Ws[k * 128 + r];
        else if (r < 256) v = Wd[k * 128 + (r - 128)];
        else              v = Wl[k * 64 + (r - 256)];
    }
    Wt[i] = (__bf16)v;
}

// ---- MFMA node GEMM tile (verified R21/R23 body; 4 waves, wave = 16 nodes x 20 col-tiles) ----
__device__ __forceinline__ bf16x8 load_af(const __bf16* p) { return *(const bf16x8*)p; }
__device__ __forceinline__ bf16x8 load_af(const float* p) {
    float4 u = *(const float4*)p;
    float4 v = *(const float4*)(p + 4);
    bf16x8 r;
    r[0] = (__bf16)u.x; r[1] = (__bf16)u.y; r[2] = (__bf16)u.z; r[3] = (__bf16)u.w;
    r[4] = (__bf16)v.x; r[5] = (__bf16)v.y; r[6] = (__bf16)v.z; r[7] = (__bf16)v.w;
    return r;
}

template <int K, typename TIN>
__device__ __forceinline__ void gemm_tile(int item, const TIN* __restrict__ xin,
        const __bf16* __restrict__ Wt,
        const float* __restrict__ a_s, const float* __restrict__ a_d,
        unsigned* __restrict__ hsb, float* __restrict__ lin,
        float* __restrict__ als, float* __restrict__ ald, char* ldsW)
{
    constexpr int NPH = (K / 64) * 2;                // 4 phases (K=128), 2 (K=64)
    const int tid  = threadIdx.x;
    const int lane = tid & 63;
    const int wave = tid >> 6;
    const int l15 = lane & 15, quad = lane >> 4;
    const int n0 = item * 64 + wave * 16;
    const int nA = min(n0 + l15, NN - 1);

    bf16x8 afr[K / 32];
#pragma unroll
    for (int ks = 0; ks < K / 32; ++ks)
        afr[ks] = load_af(xin + (size_t)nA * K + ks * 32 + quad * 8);

    const uint4* gW = (const uint4*)Wt;
    uint4* lw = (uint4*)ldsW;
    uint4 st[6];                                     // 1440 uint4 per phase (160 rows)

#pragma unroll
    for (int i = 0; i < 6; ++i) { int idx = i * 256 + tid; if (idx < 1440) st[i] = gW[idx]; }

    float4v acc[20];
#pragma unroll
    for (int t = 0; t < 20; ++t) acc[t] = (float4v){0.f, 0.f, 0.f, 0.f};

#pragma unroll
    for (int ph = 0; ph < NPH; ++ph) {
        __syncthreads();                             // prev reads (or prev item) done
#pragma unroll
        for (int i = 0; i < 6; ++i) { int idx = i * 256 + tid; if (idx < 1440) lw[idx] = st[i]; }
        __syncthreads();
        if (ph + 1 < NPH) {                          // prefetch next phase under MFMA
            const uint4* gs = gW + (ph + 1) * 1440;
#pragma unroll
            for (int i = 0; i < 6; ++i) { int idx = i * 256 + tid; if (idx < 1440) st[i] = gs[idx]; }
        }
        const int hh = ph & 1, ch = ph >> 1;
#pragma unroll
        for (int ksh = 0; ksh < 2; ++ksh) {
#pragma unroll
            for (int tl = 0; tl < 10; ++tl) {
                bf16x8 bw = *(const bf16x8*)&ldsW[(tl * 16 + l15) * 144 + (ksh * 4 + quad) * 16];
                acc[hh * 10 + tl] =
                    __builtin_amdgcn_mfma_f32_16x16x32_bf16(bw, afr[ch * 2 + ksh], acc[hh * 10 + tl], 0, 0, 0);
            }
        }
    }
    __syncthreads();                                 // protect LDS for next item

    // ---- als/ald reduce ----
    float s0 = 0.f, s1 = 0.f, d0 = 0.f, d1 = 0.f;
#pragma unroll
    for (int t = 0; t < 4; ++t) {
        float4 as0 = *(const float4*)&a_s[t * 16 + quad * 4];
        float4 as1 = *(const float4*)&a_s[64 + t * 16 + quad * 4];
        float4 ad0 = *(const float4*)&a_d[t * 16 + quad * 4];
        float4 ad1 = *(const float4*)&a_d[64 + t * 16 + quad * 4];
        s0 += acc[t][0] * as0.x + acc[t][1] * as0.y + acc[t][2] * as0.z + acc[t][3] * as0.w;
        s1 += acc[t + 4][0] * as1.x + acc[t + 4][1] * as1.y + acc[t + 4][2] * as1.z + acc[t + 4][3] * as1.w;
        d0 += acc[t + 8][0] * ad0.x + acc[t + 8][1] * ad0.y + acc[t + 8][2] * ad0.z + acc[t + 8][3] * ad0.w;
        d1 += acc[t + 12][0] * ad1.x + acc[t + 12][1] * ad1.y + acc[t + 12][2] * ad1.z + acc[t + 12][3] * ad1.w;
    }
    s0 += __shfl_xor(s0, 16); s0 += __shfl_xor(s0, 32);
    s1 += __shfl_xor(s1, 16); s1 += __shfl_xor(s1, 32);
    d0 += __shfl_xor(d0, 16); d0 += __shfl_xor(d0, 32);
    d1 += __shfl_xor(d1, 16); d1 += __shfl_xor(d1, 32);

    // ---- direct, line-complete stores (node = l15) ----
    int n = n0 + l15;
    if (n < NN) {
#pragma unroll
        for (int t = 0; t < 4; ++t) {
            uint4 u;
            u.x = pack_bf2(acc[t][0], acc[t + 4][0]);
            u.y = pack_bf2(acc[t][1], acc[t + 4][1]);
            u.z = pack_bf2(acc[t][2], acc[t + 4][2]);
            u.w = pack_bf2(acc[t][3], acc[t + 4][3]);
            *(uint4*)&hsb[(size_t)n * 64 + t * 16 + quad * 4] = u;
            *(float4*)&lin[(size_t)n * 64 + t * 16 + quad * 4] =
                make_float4(acc[16 + t][0], acc[16 + t][1], acc[16 + t][2], acc[16 + t][3]);
        }
        if (quad == 0) *(float2*)&als[(size_t)n * 2] = make_float2(s0, s1);
        if (quad == 1) *(float2*)&ald[(size_t)n * 2] = make_float2(d0, d1);
    }
}

// ---- aggregate body (verified R23; quarter-wave per edge slot, predicated) ----
__device__ __forceinline__ float2 edge_w(const float* __restrict__ als, int s,
                                         float ad0, float ad1)
{
    float2 al = *(const float2*)&als[s * 2];
    float e0 = al.x + ad0; e0 = (e0 >= 0.f) ? e0 : 0.2f * e0;
    float e1 = al.y + ad1; e1 = (e1 >= 0.f) ? e1 : 0.2f * e1;
    return make_float2(__expf(e0), __expf(e1));
}
__device__ __forceinline__ void store_q(float* p, float v0, float v1, float v2, float v3) {
    *(float4*)p = make_float4(v0, v1, v2, v3);
}
__device__ __forceinline__ void store_q(__bf16* p, float v0, float v1, float v2, float v3) {
    *(uint2*)p = make_uint2(pack_bf2(v0, v1), pack_bf2(v2, v3));
}

template <typename TO>
__device__ __forceinline__ void agg_node(int w,
        const int* __restrict__ row, const int* __restrict__ csr_src,
        const float* __restrict__ als, const float* __restrict__ ald,
        const unsigned* __restrict__ hsb, const float* __restrict__ lin,
        const float* __restrict__ b, const float* __restrict__ bl,
        TO* __restrict__ out)
{
    int lane = threadIdx.x & 63;
    int q = lane >> 4;
    int l15 = lane & 15;
    int p0 = row[w], p1 = row[w + 1];
    float ad0 = ald[w * 2 + 0];
    float ad1 = ald[w * 2 + 1];

    float a0[4] = {0.f, 0.f, 0.f, 0.f};
    float a1[4] = {0.f, 0.f, 0.f, 0.f};
    float den0 = 0.f, den1 = 0.f;

    for (int p = p0 + q; p < p1; p += 16) {
#pragma unroll
        for (int j = 0; j < 4; ++j) {
            int pp = p + 4 * j;
            bool live = (pp < p1);
            int s = csr_src[live ? pp : p0];
            float2 e = edge_w(als, s, ad0, ad1);
            if (!live) e = make_float2(0.f, 0.f);
            uint4 g = *(const uint4*)&hsb[(size_t)s * 64 + 4 * l15];
            den0 += e.x; den1 += e.y;
            float2 h;
            h = unpack_bf2(g.x); a0[0] += e.x * h.x; a1[0] += e.y * h.y;
            h = unpack_bf2(g.y); a0[1] += e.x * h.x; a1[1] += e.y * h.y;
            h = unpack_bf2(g.z); a0[2] += e.x * h.x; a1[2] += e.y * h.y;
            h = unpack_bf2(g.w); a0[3] += e.x * h.x; a1[3] += e.y * h.y;
        }
    }

#pragma unroll
    for (int i = 0; i < 4; ++i) {
        a0[i] += __shfl_xor(a0[i], 16); a0[i] += __shfl_xor(a0[i], 32);
        a1[i] += __shfl_xor(a1[i], 16); a1[i] += __shfl_xor(a1[i], 32);
    }
    den0 += __shfl_xor(den0, 16); den0 += __shfl_xor(den0, 32);
    den1 += __shfl_xor(den1, 16); den1 += __shfl_xor(den1, 32);

    if (q == 0) {
        int c0 = 4 * l15;
        float r0 = 1.f / (den0 + 1e-16f);
        float r1 = 1.f / (den1 + 1e-16f);
        float4 lv = *(const float4*)&lin[(size_t)w * 64 + c0];
        float v0 = 0.5f * (a0[0] * r0 + a1[0] * r1) + b[c0 + 0] + bl[c0 + 0] + lv.x;
        float v1 = 0.5f * (a0[1] * r0 + a1[1] * r1) + b[c0 + 1] + bl[c0 + 1] + lv.y;
        float v2 = 0.5f * (a0[2] * r0 + a1[2] * r1) + b[c0 + 2] + bl[c0 + 2] + lv.z;
        float v3 = 0.5f * (a0[3] * r0 + a1[3] * r1) + b[c0 + 3] + bl[c0 + 3] + lv.w;
        store_q(&out[(size_t)w * 64 + c0],
                fmaxf(v0, 0.f), fmaxf(v1, 0.f), fmaxf(v2, 0.f), fmaxf(v3, 0.f));
    }
}

// ============================ cooperative mega-kernel ============================
// R25: ONE dispatch replaces 9. R21/R23 counters: no hotspot, every phase
// latency-bound (MfmaUtil<3%, HBM<38%), ~312 us of phases + ~45 us of gaps.
// Grid sized to guaranteed co-residency via occupancy query (expect 1024).
// Phase plan (grid.sync between):
//  P0 convert Wt x3 + zero deg | P1 hist(rank) | P2 chunk scans(exl,bsum)
//  P3 serial top scan(boff)    | P4 gemm1 + row + scatter (mixed stride)
//  P5 agg1->hb | P6 gemm2 | P7 agg2->hb | P8 gemm3 | P9 agg3->out
__global__ void __launch_bounds__(256, 4)
mega_kernel(MegaArgs A)
{
    __shared__ __align__(16) char lds[160 * 144];    // 23040 B (gemm stage / scan)
    cg::grid_group grid = cg::this_grid();
    const int G = gridDim.x;
    const int tid = threadIdx.x;

    // ---- P0: weight convert + deg zero ----
    for (int u = blockIdx.x; u < CVU + ZU; u += G) {
        if (u < CVU) {
            int i = u * 256 + tid;                   // [0, 92160)
            if (i < 46080)      convert_w_part(A.Ws[0], A.Wd[0], A.Wl[0], A.Wt1, i);
            else if (i < 69120) convert_w_part(A.Ws[1], A.Wd[1], A.Wl[1], A.Wt2, i - 46080);
            else                convert_w_part(A.Ws[2], A.Wd[2], A.Wl[2], A.Wt3, i - 69120);
        } else {
            int i = (u - CVU) * 256 + tid;
            if (i < NN) A.deg[i] = 0;
        }
    }
    grid.sync();

    // ---- P1: histogram + rank ----
    for (int u = blockIdx.x; u < EBU; u += G) {
        int e = u * 256 + tid;
        if (e < NE) A.rank[e] = atomicAdd(&A.deg[A.ei[NE + e]], 1);
    }
    grid.sync();

    // ---- P2: per-256-chunk scans ----
    {
        int* sh = (int*)lds;
        for (int u = blockIdx.x; u < NCH; u += G) {
            int i = u * 256 + tid;
            int v = (i < NN) ? A.deg[i] : 0;
            sh[tid] = v;
            __syncthreads();
            for (int off = 1; off < 256; off <<= 1) {
                int t = (tid >= off) ? sh[tid - off] : 0;
                __syncthreads();
                sh[tid] += t;
                __syncthreads();
            }
            if (i < NN) A.exl[i] = sh[tid] - v;
            if (tid == 255) A.bsum[u] = sh[255];
            __syncthreads();
        }
    }
    grid.sync();

    // ---- P3: top scan (196 values, serial -- trivial) ----
    if (blockIdx.x == 0 && tid == 0) {
        int run = 0;
        for (int c = 0; c < NCH; ++c) { A.boff[c] = run; run += A.bsum[c]; }
    }
    grid.sync();

    // ---- P4: gemm1 + row materialization + edge scatter (mixed work units) ----
    for (int u = blockIdx.x; u < GBU + RBU + EBU; u += G) {
        if (u < GBU) {
            gemm_tile<128, float>(u, A.x, A.Wt1, A.as[0], A.ad[0],
                                  A.hsb, A.lin, A.als, A.ald, lds);
        } else if (u < GBU + RBU) {
            int i = (u - GBU) * 256 + tid;
            if (i < NN)       A.row[i] = A.exl[i] + A.boff[i >> 8];
            else if (i == NN) A.row[i] = NE;
        } else {
            int e = (u - GBU - RBU) * 256 + tid;
            if (e < NE) {
                int s = A.ei[e], d = A.ei[NE + e];
                A.csr_src[A.exl[d] + A.boff[d >> 8] + A.rank[e]] = s;
            }
        }
    }
    grid.sync();

    // ---- P5: agg1 -> hb ----
    for (int u = blockIdx.x; u < AGU; u += G) {
        int w = u * 4 + (tid >> 6);
        if (w < NN) agg_node<__bf16>(w, A.row, A.csr_src, A.als, A.ald,
                                     A.hsb, A.lin, A.bb[0], A.bl[0], A.hb);
    }
    grid.sync();

    // ---- P6: gemm2 ----
    for (int u = blockIdx.x; u < GBU; u += G)
        gemm_tile<64, __bf16>(u, A.hb, A.Wt2, A.as[1], A.ad[1],
                              A.hsb, A.lin, A.als, A.ald, lds);
    grid.sync();

    // ---- P7: agg2 -> hb ----
    for (int u = blockIdx.x; u < AGU; u += G) {
        int w = u * 4 + (tid >> 6);
        if (w < NN) agg_node<__bf16>(w, A.row, A.csr_src, A.als, A.ald,
                                     A.hsb, A.lin, A.bb[1], A.bl[1], A.hb);
    }
    grid.sync();

    // ---- P8: gemm3 ----
    for (int u = blockIdx.x; u < GBU; u += G)
        gemm_tile<64, __bf16>(u, A.hb, A.Wt3, A.as[2], A.ad[2],
                              A.hsb, A.lin, A.als, A.ald, lds);
    grid.sync();

    // ---- P9: agg3 -> out ----
    for (int u = blockIdx.x; u < AGU; u += G) {
        int w = u * 4 + (tid >> 6);
        if (w < NN) agg_node<float>(w, A.row, A.csr_src, A.als, A.ald,
                                    A.hsb, A.lin, A.bb[2], A.bl[2], A.out);
    }
}

// ============================ launch ============================

extern "C" void kernel_launch(void* const* d_in, const int* in_sizes, int n_in,
                              void* d_out, int out_size, void* d_ws, size_t ws_size,
                              hipStream_t stream)
{
    MegaArgs A;
    A.x  = (const float*)d_in[0];
    A.ei = (const int*)d_in[1];
    for (int l = 0; l < 3; ++l) {
        int base = 2 + 7 * l;
        A.Ws[l] = (const float*)d_in[base + 0];
        A.Wd[l] = (const float*)d_in[base + 1];
        A.as[l] = (const float*)d_in[base + 2];
        A.ad[l] = (const float*)d_in[base + 3];
        A.bb[l] = (const float*)d_in[base + 4];
        A.Wl[l] = (const float*)d_in[base + 5];
        A.bl[l] = (const float*)d_in[base + 6];
    }

    float* ws = (float*)d_ws;
    A.hsb = (unsigned*)ws;                           // NN*64 packed bf16x2
    A.lin = (float*)(A.hsb + (size_t)NN * 64);       // NN*64 f32
    A.als = A.lin + (size_t)NN * 64;                 // NN*2
    A.ald = A.als + (size_t)NN * 2;                  // NN*2
    A.hb  = (__bf16*)(A.ald + (size_t)NN * 2);       // NN*64 bf16
    A.Wt1 = A.hb + (size_t)NN * 64;                  // 2*320*72
    A.Wt2 = A.Wt1 + 2 * 320 * 72;                    // 320*72
    A.Wt3 = A.Wt2 + 320 * 72;                        // 320*72
    A.row = (int*)(A.Wt3 + 320 * 72);                // NN+1
    A.deg = A.row + (NN + 1);                        // NN
    A.rank = A.deg + NN;                             // NE
    A.exl  = A.rank + NE;                            // NN
    A.bsum = A.exl + NN;                             // NCH
    A.boff = A.bsum + NCH;                           // NCH
    A.csr_src = A.boff + NCH;                        // NE
    A.out = (float*)d_out;

    static int grid = 0;
    if (grid == 0) {
        int bpc = 0, ncu = 0, dev = 0;
        hipGetDevice(&dev);
        hipOccupancyMaxActiveBlocksPerMultiprocessor(&bpc, (const void*)mega_kernel, 256, 0);
        hipDeviceGetAttribute(&ncu, hipDeviceAttributeMultiprocessorCount, dev);
        if (bpc < 1) bpc = 1;
        if (ncu < 1) ncu = 256;
        grid = bpc * ncu;
        if (grid > 4096) grid = 4096;
    }

    void* kargs[] = { (void*)&A };
    hipLaunchCooperativeKernel((const void*)mega_kernel, dim3(grid), dim3(256),
                               kargs, 0, stream);
}

// Round 7
// 388.599 us; speedup vs baseline: 2.6764x; 2.6764x over previous
//
#include <hip/hip_runtime.h>
#include <hip/hip_bf16.h>

#define NN 50000
#define NE 800000
#define SCAN_BS 1024
#define SCAN_NB ((NN + SCAN_BS - 1) / SCAN_BS)   // 49
#define EB ((NE + 255) / 256)                    // 3125 edge blocks
#define GB ((NN + 63) / 64)                      // 782 gemm blocks
#define RB ((NN + 1 + 255) / 256)                // 196 row blocks

typedef __attribute__((ext_vector_type(8))) __bf16 bf16x8;
typedef __attribute__((ext_vector_type(4))) float float4v;

__device__ __forceinline__ unsigned pack_bf2(float lo, float hi) {
    union { __bf16 b; unsigned short u; } a, c;
    a.b = (__bf16)lo; c.b = (__bf16)hi;
    return (unsigned)a.u | ((unsigned)c.u << 16);
}
__device__ __forceinline__ float2 unpack_bf2(unsigned v) {
    union { unsigned short u; __bf16 b; } lo, hi;
    lo.u = (unsigned short)(v & 0xffff); hi.u = (unsigned short)(v >> 16);
    return make_float2((float)lo.b, (float)hi.b);
}

// ================= fused prep: hist (edges) + 3x convert_w (grid-partitioned) =================
// Wt PRE-PADDED in 64-k chunks: [NC][320][72] bf16 (row stride 144 B).
// Rows 0..127 = Ws cols, 128..255 = Wd cols, 256..319 = Wl cols. Pad cols 64..71 = 0.

__device__ __forceinline__ void convert_w_part(const float* __restrict__ Ws,
                                               const float* __restrict__ Wd,
                                               const float* __restrict__ Wl,
                                               __bf16* __restrict__ Wt, int NC, int i)
{
    if (i >= NC * 23040) return;           // 23040 = 320*72 per chunk
    int chunk = i / 23040, rem = i % 23040;
    int r = rem / 72, c = rem % 72;
    float v = 0.f;
    if (c < 64) {
        int k = chunk * 64 + c;
        if (r < 128)      v = Ws[k * 128 + r];
        else if (r < 256) v = Wd[k * 128 + (r - 128)];
        else              v = Wl[k * 64 + (r - 256)];
    }
    Wt[i] = (__bf16)v;
}

__global__ void __launch_bounds__(256)
prep_kernel(const int* __restrict__ ei, int* __restrict__ deg, int* __restrict__ rank,
            const float* __restrict__ Ws1, const float* __restrict__ Wd1,
            const float* __restrict__ Wl1, __bf16* __restrict__ Wt1,
            const float* __restrict__ Ws2, const float* __restrict__ Wd2,
            const float* __restrict__ Wl2, __bf16* __restrict__ Wt2,
            const float* __restrict__ Ws3, const float* __restrict__ Wd3,
            const float* __restrict__ Wl3, __bf16* __restrict__ Wt3)
{
    int bi = blockIdx.x;
    if (bi < EB) {
        int e = bi * 256 + threadIdx.x;
        if (e < NE) rank[e] = atomicAdd(&deg[ei[NE + e]], 1);
    } else if (bi < EB + 180) {            // layer1: 2 chunks = 46080 elems
        convert_w_part(Ws1, Wd1, Wl1, Wt1, 2, (bi - EB) * 256 + threadIdx.x);
    } else if (bi < EB + 270) {            // layer2: 1 chunk = 23040
        convert_w_part(Ws2, Wd2, Wl2, Wt2, 1, (bi - EB - 180) * 256 + threadIdx.x);
    } else {                               // layer3
        convert_w_part(Ws3, Wd3, Wl3, Wt3, 1, (bi - EB - 270) * 256 + threadIdx.x);
    }
}

// ============================ fused scan (block scan + last-block top scan) ============================

__global__ void __launch_bounds__(SCAN_BS)
scan12_kernel(const int* __restrict__ deg, int* __restrict__ exl,
              int* __restrict__ bsum, int* __restrict__ boff, int* __restrict__ ticket)
{
    __shared__ int sh[SCAN_BS];
    __shared__ int lastFlag;
    int t = threadIdx.x;
    int i = blockIdx.x * SCAN_BS + t;
    int v = (i < NN) ? deg[i] : 0;
    sh[t] = v;
    __syncthreads();
    for (int off = 1; off < SCAN_BS; off <<= 1) {
        int u = (t >= off) ? sh[t - off] : 0;
        __syncthreads();
        sh[t] += u;
        __syncthreads();
    }
    if (i < NN) exl[i] = sh[t] - v;
    if (t == SCAN_BS - 1) {
        bsum[blockIdx.x] = sh[t];
        __threadfence();
        lastFlag = (atomicAdd(ticket, 1) == SCAN_NB - 1);
    }
    __syncthreads();
    if (lastFlag && t < 64) {
        __threadfence();
        int l = t;
        int bv = (l < SCAN_NB) ? bsum[l] : 0;
        int own = bv;
        for (int off = 1; off < 64; off <<= 1) {
            int u = __shfl_up(bv, off);
            if (l >= off) bv += u;
        }
        if (l < SCAN_NB) boff[l] = bv - own;
    }
}

// ============================ MFMA node GEMM (layer 1; half-tile staging + fused CSR tail) ============================

__device__ __forceinline__ bf16x8 load_af(const __bf16* p) { return *(const bf16x8*)p; }
__device__ __forceinline__ bf16x8 load_af(const float* p) {
    float4 u = *(const float4*)p;
    float4 v = *(const float4*)(p + 4);
    bf16x8 r;
    r[0] = (__bf16)u.x; r[1] = (__bf16)u.y; r[2] = (__bf16)u.z; r[3] = (__bf16)u.w;
    r[4] = (__bf16)v.x; r[5] = (__bf16)v.y; r[6] = (__bf16)v.z; r[7] = (__bf16)v.w;
    return r;
}

template <int K, typename TIN, bool FUSE>
__global__ void __launch_bounds__(256, 4)
mfma_gemm(const TIN* __restrict__ xin, const __bf16* __restrict__ Wt,
          const float* __restrict__ a_s, const float* __restrict__ a_d,
          unsigned* __restrict__ hsb, float* __restrict__ lin,
          float* __restrict__ als, float* __restrict__ ald,
          const int* __restrict__ ei, const int* __restrict__ rank,
          const int* __restrict__ exl, const int* __restrict__ boff,
          int* __restrict__ row, int* __restrict__ csr_src)
{
    const int tid = threadIdx.x;

    if (FUSE && blockIdx.x >= GB) {
        int bi = blockIdx.x - GB;
        if (bi < RB) {
            int i = bi * 256 + tid;
            if (i < NN)       row[i] = exl[i] + boff[i >> 10];
            else if (i == NN) row[i] = NE;
        } else {
            int e = (bi - RB) * 256 + tid;
            if (e < NE) {
                int s = ei[e], d = ei[NE + e];
                csr_src[exl[d] + boff[d >> 10] + rank[e]] = s;
            }
        }
        return;
    }

    constexpr int NPH = (K / 64) * 2;                // 4 phases (K=128)
    __shared__ __align__(16) char ldsW[160 * 144];   // 23040 B

    const int lane = tid & 63;
    const int wave = tid >> 6;
    const int l15 = lane & 15, quad = lane >> 4;
    const int n0 = blockIdx.x * 64 + wave * 16;
    const int nA = min(n0 + l15, NN - 1);

    bf16x8 afr[K / 32];
#pragma unroll
    for (int ks = 0; ks < K / 32; ++ks)
        afr[ks] = load_af(xin + (size_t)nA * K + ks * 32 + quad * 8);

    const uint4* gW = (const uint4*)Wt;
    uint4* lw = (uint4*)ldsW;
    uint4 st[6];                                     // 1440 uint4 per phase

#pragma unroll
    for (int i = 0; i < 6; ++i) { int idx = i * 256 + tid; if (idx < 1440) st[i] = gW[idx]; }

    float4v acc[20];
#pragma unroll
    for (int t = 0; t < 20; ++t) acc[t] = (float4v){0.f, 0.f, 0.f, 0.f};

#pragma unroll
    for (int ph = 0; ph < NPH; ++ph) {
        if (ph) __syncthreads();
#pragma unroll
        for (int i = 0; i < 6; ++i) { int idx = i * 256 + tid; if (idx < 1440) lw[idx] = st[i]; }
        __syncthreads();
        if (ph + 1 < NPH) {
            const uint4* gs = gW + (ph + 1) * 1440;
#pragma unroll
            for (int i = 0; i < 6; ++i) { int idx = i * 256 + tid; if (idx < 1440) st[i] = gs[idx]; }
        }
        const int hh = ph & 1, ch = ph >> 1;
#pragma unroll
        for (int ksh = 0; ksh < 2; ++ksh) {
#pragma unroll
            for (int tl = 0; tl < 10; ++tl) {
                bf16x8 bw = *(const bf16x8*)&ldsW[(tl * 16 + l15) * 144 + (ksh * 4 + quad) * 16];
                acc[hh * 10 + tl] =
                    __builtin_amdgcn_mfma_f32_16x16x32_bf16(bw, afr[ch * 2 + ksh], acc[hh * 10 + tl], 0, 0, 0);
            }
        }
    }

    float s0 = 0.f, s1 = 0.f, d0 = 0.f, d1 = 0.f;
#pragma unroll
    for (int t = 0; t < 4; ++t) {
        float4 as0 = *(const float4*)&a_s[t * 16 + quad * 4];
        float4 as1 = *(const float4*)&a_s[64 + t * 16 + quad * 4];
        float4 ad0 = *(const float4*)&a_d[t * 16 + quad * 4];
        float4 ad1 = *(const float4*)&a_d[64 + t * 16 + quad * 4];
        s0 += acc[t][0] * as0.x + acc[t][1] * as0.y + acc[t][2] * as0.z + acc[t][3] * as0.w;
        s1 += acc[t + 4][0] * as1.x + acc[t + 4][1] * as1.y + acc[t + 4][2] * as1.z + acc[t + 4][3] * as1.w;
        d0 += acc[t + 8][0] * ad0.x + acc[t + 8][1] * ad0.y + acc[t + 8][2] * ad0.z + acc[t + 8][3] * ad0.w;
        d1 += acc[t + 12][0] * ad1.x + acc[t + 12][1] * ad1.y + acc[t + 12][2] * ad1.z + acc[t + 12][3] * ad1.w;
    }
    s0 += __shfl_xor(s0, 16); s0 += __shfl_xor(s0, 32);
    s1 += __shfl_xor(s1, 16); s1 += __shfl_xor(s1, 32);
    d0 += __shfl_xor(d0, 16); d0 += __shfl_xor(d0, 32);
    d1 += __shfl_xor(d1, 16); d1 += __shfl_xor(d1, 32);

    int n = n0 + l15;
    if (n < NN) {
#pragma unroll
        for (int t = 0; t < 4; ++t) {
            uint4 u;
            u.x = pack_bf2(acc[t][0], acc[t + 4][0]);
            u.y = pack_bf2(acc[t][1], acc[t + 4][1]);
            u.z = pack_bf2(acc[t][2], acc[t + 4][2]);
            u.w = pack_bf2(acc[t][3], acc[t + 4][3]);
            *(uint4*)&hsb[(size_t)n * 64 + t * 16 + quad * 4] = u;
            *(float4*)&lin[(size_t)n * 64 + t * 16 + quad * 4] =
                make_float4(acc[16 + t][0], acc[16 + t][1], acc[16 + t][2], acc[16 + t][3]);
        }
        if (quad == 0) *(float2*)&als[(size_t)n * 2] = make_float2(s0, s1);
        if (quad == 1) *(float2*)&ald[(size_t)n * 2] = make_float2(d0, d1);
    }
}

// ============================ aggregate helpers ============================

__device__ __forceinline__ float2 edge_w(const float* __restrict__ als, int s,
                                         float ad0, float ad1)
{
    float2 al = *(const float2*)&als[s * 2];
    float e0 = al.x + ad0; e0 = (e0 >= 0.f) ? e0 : 0.2f * e0;
    float e1 = al.y + ad1; e1 = (e1 >= 0.f) ? e1 : 0.2f * e1;
    return make_float2(__expf(e0), __expf(e1));
}

__device__ __forceinline__ void store_q(float* p, float v0, float v1, float v2, float v3) {
    *(float4*)p = make_float4(v0, v1, v2, v3);
}
__device__ __forceinline__ void store_q(__bf16* p, float v0, float v1, float v2, float v3) {
    *(uint2*)p = make_uint2(pack_bf2(v0, v1), pack_bf2(v2, v3));
}

// ============================ fused agg_l + gemm_{l+1} (R27) ============================
// Block = 64 nodes. Phase A: 4 waves x 16 sequential nodes aggregate layer-l
// output (reads ping set P) into h_lds (bf16, stride 144 B). Phase B: the
// verified K=64 MFMA tile reading A-fragments from h_lds, writing pong set Q.
// Ping-pong removes the intra-dispatch race (other blocks' agg still reads P
// while this block's gemm writes Q). hb round-trip + 2 dispatch boundaries gone.
__global__ void __launch_bounds__(256, 4)
fused_agg_gemm(const int* __restrict__ row, const int* __restrict__ csr_src,
               const float* __restrict__ alsP, const float* __restrict__ aldP,
               const unsigned* __restrict__ hsbP, const float* __restrict__ linP,
               const float* __restrict__ bP, const float* __restrict__ blP,
               const __bf16* __restrict__ Wt,
               const float* __restrict__ a_s, const float* __restrict__ a_d,
               unsigned* __restrict__ hsbQ, float* __restrict__ linQ,
               float* __restrict__ alsQ, float* __restrict__ aldQ)
{
    __shared__ __align__(16) char ldsW[160 * 144];   // 23040 B gemm staging
    __shared__ __align__(16) char h_lds[64 * 144];   // 9216 B agg output tile

    const int tid  = threadIdx.x;
    const int lane = tid & 63;
    const int wave = tid >> 6;
    const int q    = lane >> 4;
    const int l15  = lane & 15;
    const int nblk = blockIdx.x * 64;

    {   // zero h tile (pad slots for n >= NN must not feed NaN into MFMA)
        uint4* hz = (uint4*)h_lds;
        for (int i = tid; i < 576; i += 256) hz[i] = (uint4){0u, 0u, 0u, 0u};
    }
    __syncthreads();

    // ---- Phase A: aggregate 16 nodes per wave ----
    for (int i = 0; i < 16; ++i) {
        int w = nblk + wave * 16 + i;
        if (w >= NN) break;
        int p0 = row[w], p1 = row[w + 1];
        float ad0 = aldP[w * 2 + 0];
        float ad1 = aldP[w * 2 + 1];
        float a0[4] = {0.f, 0.f, 0.f, 0.f};
        float a1[4] = {0.f, 0.f, 0.f, 0.f};
        float den0 = 0.f, den1 = 0.f;

        for (int p = p0 + q; p < p1; p += 16) {
#pragma unroll
            for (int j = 0; j < 4; ++j) {
                int pp = p + 4 * j;
                bool live = (pp < p1);
                int s = csr_src[live ? pp : p0];
                float2 e = edge_w(alsP, s, ad0, ad1);
                if (!live) e = make_float2(0.f, 0.f);
                uint4 g = *(const uint4*)&hsbP[(size_t)s * 64 + 4 * l15];
                den0 += e.x; den1 += e.y;
                float2 h;
                h = unpack_bf2(g.x); a0[0] += e.x * h.x; a1[0] += e.y * h.y;
                h = unpack_bf2(g.y); a0[1] += e.x * h.x; a1[1] += e.y * h.y;
                h = unpack_bf2(g.z); a0[2] += e.x * h.x; a1[2] += e.y * h.y;
                h = unpack_bf2(g.w); a0[3] += e.x * h.x; a1[3] += e.y * h.y;
            }
        }
#pragma unroll
        for (int k = 0; k < 4; ++k) {
            a0[k] += __shfl_xor(a0[k], 16); a0[k] += __shfl_xor(a0[k], 32);
            a1[k] += __shfl_xor(a1[k], 16); a1[k] += __shfl_xor(a1[k], 32);
        }
        den0 += __shfl_xor(den0, 16); den0 += __shfl_xor(den0, 32);
        den1 += __shfl_xor(den1, 16); den1 += __shfl_xor(den1, 32);

        if (q == 0) {
            int c0 = 4 * l15;
            float r0 = 1.f / (den0 + 1e-16f);
            float r1 = 1.f / (den1 + 1e-16f);
            float4 lv = *(const float4*)&linP[(size_t)w * 64 + c0];
            float v0 = fmaxf(0.5f * (a0[0] * r0 + a1[0] * r1) + bP[c0 + 0] + blP[c0 + 0] + lv.x, 0.f);
            float v1 = fmaxf(0.5f * (a0[1] * r0 + a1[1] * r1) + bP[c0 + 1] + blP[c0 + 1] + lv.y, 0.f);
            float v2 = fmaxf(0.5f * (a0[2] * r0 + a1[2] * r1) + bP[c0 + 2] + blP[c0 + 2] + lv.z, 0.f);
            float v3 = fmaxf(0.5f * (a0[3] * r0 + a1[3] * r1) + bP[c0 + 3] + blP[c0 + 3] + lv.w, 0.f);
            int slot = wave * 16 + i;
            *(uint2*)&h_lds[slot * 144 + 8 * l15] =
                make_uint2(pack_bf2(v0, v1), pack_bf2(v2, v3));
        }
    }
    __syncthreads();

    // ---- Phase B: K=64 MFMA tile, A-fragments from h_lds ----
    bf16x8 afr[2];
    afr[0] = *(const bf16x8*)&h_lds[(wave * 16 + l15) * 144 + 0  + q * 16];
    afr[1] = *(const bf16x8*)&h_lds[(wave * 16 + l15) * 144 + 64 + q * 16];

    const uint4* gW = (const uint4*)Wt;
    uint4* lw = (uint4*)ldsW;
    uint4 st[6];
#pragma unroll
    for (int i = 0; i < 6; ++i) { int idx = i * 256 + tid; if (idx < 1440) st[i] = gW[idx]; }

    float4v acc[20];
#pragma unroll
    for (int t = 0; t < 20; ++t) acc[t] = (float4v){0.f, 0.f, 0.f, 0.f};

#pragma unroll
    for (int ph = 0; ph < 2; ++ph) {
        if (ph) __syncthreads();
#pragma unroll
        for (int i = 0; i < 6; ++i) { int idx = i * 256 + tid; if (idx < 1440) lw[idx] = st[i]; }
        __syncthreads();
        if (ph == 0) {
            const uint4* gs = gW + 1440;
#pragma unroll
            for (int i = 0; i < 6; ++i) { int idx = i * 256 + tid; if (idx < 1440) st[i] = gs[idx]; }
        }
#pragma unroll
        for (int ksh = 0; ksh < 2; ++ksh) {
#pragma unroll
            for (int tl = 0; tl < 10; ++tl) {
                bf16x8 bw = *(const bf16x8*)&ldsW[(tl * 16 + l15) * 144 + (ksh * 4 + q) * 16];
                acc[ph * 10 + tl] =
                    __builtin_amdgcn_mfma_f32_16x16x32_bf16(bw, afr[ksh], acc[ph * 10 + tl], 0, 0, 0);
            }
        }
    }

    float s0 = 0.f, s1 = 0.f, d0 = 0.f, d1 = 0.f;
#pragma unroll
    for (int t = 0; t < 4; ++t) {
        float4 as0 = *(const float4*)&a_s[t * 16 + q * 4];
        float4 as1 = *(const float4*)&a_s[64 + t * 16 + q * 4];
        float4 ad0 = *(const float4*)&a_d[t * 16 + q * 4];
        float4 ad1 = *(const float4*)&a_d[64 + t * 16 + q * 4];
        s0 += acc[t][0] * as0.x + acc[t][1] * as0.y + acc[t][2] * as0.z + acc[t][3] * as0.w;
        s1 += acc[t + 4][0] * as1.x + acc[t + 4][1] * as1.y + acc[t + 4][2] * as1.z + acc[t + 4][3] * as1.w;
        d0 += acc[t + 8][0] * ad0.x + acc[t + 8][1] * ad0.y + acc[t + 8][2] * ad0.z + acc[t + 8][3] * ad0.w;
        d1 += acc[t + 12][0] * ad1.x + acc[t + 12][1] * ad1.y + acc[t + 12][2] * ad1.z + acc[t + 12][3] * ad1.w;
    }
    s0 += __shfl_xor(s0, 16); s0 += __shfl_xor(s0, 32);
    s1 += __shfl_xor(s1, 16); s1 += __shfl_xor(s1, 32);
    d0 += __shfl_xor(d0, 16); d0 += __shfl_xor(d0, 32);
    d1 += __shfl_xor(d1, 16); d1 += __shfl_xor(d1, 32);

    int n = nblk + wave * 16 + l15;
    if (n < NN) {
#pragma unroll
        for (int t = 0; t < 4; ++t) {
            uint4 u;
            u.x = pack_bf2(acc[t][0], acc[t + 4][0]);
            u.y = pack_bf2(acc[t][1], acc[t + 4][1]);
            u.z = pack_bf2(acc[t][2], acc[t + 4][2]);
            u.w = pack_bf2(acc[t][3], acc[t + 4][3]);
            *(uint4*)&hsbQ[(size_t)n * 64 + t * 16 + q * 4] = u;
            *(float4*)&linQ[(size_t)n * 64 + t * 16 + q * 4] =
                make_float4(acc[16 + t][0], acc[16 + t][1], acc[16 + t][2], acc[16 + t][3]);
        }
        if (q == 0) *(float2*)&alsQ[(size_t)n * 2] = make_float2(s0, s1);
        if (q == 1) *(float2*)&aldQ[(size_t)n * 2] = make_float2(d0, d1);
    }
}

// ============================ standalone aggregate (final layer) ============================

template <typename TO>
__global__ void __launch_bounds__(256, 8)
gat_aggregate(const int* __restrict__ row, const int* __restrict__ csr_src,
              const float* __restrict__ als, const float* __restrict__ ald,
              const unsigned* __restrict__ hsb, const float* __restrict__ lin,
              const float* __restrict__ b, const float* __restrict__ bl,
              TO* __restrict__ out)
{
    int w = (blockIdx.x * 256 + threadIdx.x) >> 6;
    int lane = threadIdx.x & 63;
    int q = lane >> 4;
    int l15 = lane & 15;
    if (w >= NN) return;
    int p0 = row[w], p1 = row[w + 1];
    float ad0 = ald[w * 2 + 0];
    float ad1 = ald[w * 2 + 1];

    float a0[4] = {0.f, 0.f, 0.f, 0.f};
    float a1[4] = {0.f, 0.f, 0.f, 0.f};
    float den0 = 0.f, den1 = 0.f;

    for (int p = p0 + q; p < p1; p += 16) {
#pragma unroll
        for (int j = 0; j < 4; ++j) {
            int pp = p + 4 * j;
            bool live = (pp < p1);
            int s = csr_src[live ? pp : p0];
            float2 e = edge_w(als, s, ad0, ad1);
            if (!live) e = make_float2(0.f, 0.f);
            uint4 g = *(const uint4*)&hsb[(size_t)s * 64 + 4 * l15];
            den0 += e.x; den1 += e.y;
            float2 h;
            h = unpack_bf2(g.x); a0[0] += e.x * h.x; a1[0] += e.y * h.y;
            h = unpack_bf2(g.y); a0[1] += e.x * h.x; a1[1] += e.y * h.y;
            h = unpack_bf2(g.z); a0[2] += e.x * h.x; a1[2] += e.y * h.y;
            h = unpack_bf2(g.w); a0[3] += e.x * h.x; a1[3] += e.y * h.y;
        }
    }

#pragma unroll
    for (int i = 0; i < 4; ++i) {
        a0[i] += __shfl_xor(a0[i], 16); a0[i] += __shfl_xor(a0[i], 32);
        a1[i] += __shfl_xor(a1[i], 16); a1[i] += __shfl_xor(a1[i], 32);
    }
    den0 += __shfl_xor(den0, 16); den0 += __shfl_xor(den0, 32);
    den1 += __shfl_xor(den1, 16); den1 += __shfl_xor(den1, 32);

    if (q == 0) {
        int c0 = 4 * l15;
        float r0 = 1.f / (den0 + 1e-16f);
        float r1 = 1.f / (den1 + 1e-16f);
        float4 lv = *(const float4*)&lin[(size_t)w * 64 + c0];
        float v0 = 0.5f * (a0[0] * r0 + a1[0] * r1) + b[c0 + 0] + bl[c0 + 0] + lv.x;
        float v1 = 0.5f * (a0[1] * r0 + a1[1] * r1) + b[c0 + 1] + bl[c0 + 1] + lv.y;
        float v2 = 0.5f * (a0[2] * r0 + a1[2] * r1) + b[c0 + 2] + bl[c0 + 2] + lv.z;
        float v3 = 0.5f * (a0[3] * r0 + a1[3] * r1) + b[c0 + 3] + bl[c0 + 3] + lv.w;
        store_q(&out[(size_t)w * 64 + c0],
                fmaxf(v0, 0.f), fmaxf(v1, 0.f), fmaxf(v2, 0.f), fmaxf(v3, 0.f));
    }
}

// ============================ launch ============================

extern "C" void kernel_launch(void* const* d_in, const int* in_sizes, int n_in,
                              void* d_out, int out_size, void* d_ws, size_t ws_size,
                              hipStream_t stream)
{
    const float* x  = (const float*)d_in[0];
    const int*   ei = (const int*)d_in[1];
    const float* Ws[3]; const float* Wd[3]; const float* As[3]; const float* Ad[3];
    const float* Bb[3]; const float* Wl[3]; const float* Bl[3];
    for (int l = 0; l < 3; ++l) {
        int base = 2 + 7 * l;
        Ws[l] = (const float*)d_in[base + 0];
        Wd[l] = (const float*)d_in[base + 1];
        As[l] = (const float*)d_in[base + 2];
        Ad[l] = (const float*)d_in[base + 3];
        Bb[l] = (const float*)d_in[base + 4];
        Wl[l] = (const float*)d_in[base + 5];
        Bl[l] = (const float*)d_in[base + 6];
    }

    float* ws = (float*)d_ws;
    unsigned* hsbA = (unsigned*)ws;                  // NN*64
    float* linA = (float*)(hsbA + (size_t)NN * 64);  // NN*64
    unsigned* hsbB = (unsigned*)(linA + (size_t)NN * 64); // NN*64
    float* linB = (float*)(hsbB + (size_t)NN * 64);  // NN*64
    float* alsA = linB + (size_t)NN * 64;            // NN*2
    float* aldA = alsA + (size_t)NN * 2;             // NN*2
    float* alsB = aldA + (size_t)NN * 2;             // NN*2
    float* aldB = alsB + (size_t)NN * 2;             // NN*2
    __bf16* Wt1 = (__bf16*)(aldB + (size_t)NN * 2);  // 2*320*72
    __bf16* Wt2 = Wt1 + 2 * 320 * 72;                // 320*72
    __bf16* Wt3 = Wt2 + 320 * 72;                    // 320*72
    int* row     = (int*)(Wt3 + 320 * 72);           // NN+1
    int* deg     = row + (NN + 1);                   // NN
    int* ticket  = deg + NN;                         // 1 (zeroed with deg)
    int* rank    = ticket + 1;                       // NE
    int* exl     = rank + NE;                        // NN
    int* bsum    = exl + NN;                         // SCAN_NB
    int* boff    = bsum + SCAN_NB;                   // SCAN_NB
    int* csr_src = boff + SCAN_NB;                   // NE

    const int WB = (NN * 64 + 255) / 256;

    // --- CSR front pipeline ---
    hipMemsetAsync(deg, 0, sizeof(int) * (NN + 1), stream);   // deg + ticket
    prep_kernel<<<EB + 360, 256, 0, stream>>>(ei, deg, rank,
        Ws[0], Wd[0], Wl[0], Wt1,
        Ws[1], Wd[1], Wl[1], Wt2,
        Ws[2], Wd[2], Wl[2], Wt3);
    scan12_kernel<<<SCAN_NB, SCAN_BS, 0, stream>>>(deg, exl, bsum, boff, ticket);

    // layer-1 GEMM (writes set A) + fused CSR finish
    mfma_gemm<128, float, true><<<GB + RB + EB, 256, 0, stream>>>(
        x, Wt1, As[0], Ad[0], hsbA, linA, alsA, aldA,
        ei, rank, exl, boff, row, csr_src);

    // agg1 + gemm2: read A, write B
    fused_agg_gemm<<<GB, 256, 0, stream>>>(
        row, csr_src, alsA, aldA, hsbA, linA, Bb[0], Bl[0],
        Wt2, As[1], Ad[1], hsbB, linB, alsB, aldB);

    // agg2 + gemm3: read B, write A
    fused_agg_gemm<<<GB, 256, 0, stream>>>(
        row, csr_src, alsB, aldB, hsbB, linB, Bb[1], Bl[1],
        Wt3, As[2], Ad[2], hsbA, linA, alsA, aldA);

    // agg3: read A -> out
    gat_aggregate<float><<<WB, 256, 0, stream>>>(
        row, csr_src, alsA, aldA, hsbA, linA, Bb[2], Bl[2], (float*)d_out);
}